// Round 6
// baseline (487.721 us; speedup 1.0000x reference)
//
#include <hip/hip_runtime.h>
#include <cfloat>

#define BB 64
#define NN 1024
#define MM 128
#define DD 256
#define MASKV (-1e30f)

typedef __attribute__((ext_vector_type(8))) short bf16x8;
typedef __attribute__((ext_vector_type(16))) float f32x16;

__device__ __forceinline__ unsigned short f2bf(float x) {
  union { float f; unsigned int u; } v; v.f = x;
  unsigned int r = v.u + 0x7fffu + ((v.u >> 16) & 1u);   // round-to-nearest-even
  return (unsigned short)(r >> 16);
}
__device__ __forceinline__ float bf2f(unsigned short h) {
  union { float f; unsigned int u; } v; v.u = ((unsigned int)h) << 16;
  return v.f;
}
__device__ __forceinline__ void split8(const float* xs, uint4* hv, uint4* lv) {
  unsigned hp[4], lp[4];
  #pragma unroll
  for (int p = 0; p < 4; p++) {
    unsigned short h0 = f2bf(xs[2 * p]), h1 = f2bf(xs[2 * p + 1]);
    unsigned short g0 = f2bf(xs[2 * p] - bf2f(h0));
    unsigned short g1 = f2bf(xs[2 * p + 1] - bf2f(h1));
    hp[p] = (unsigned)h0 | ((unsigned)h1 << 16);
    lp[p] = (unsigned)g0 | ((unsigned)g1 << 16);
  }
  *hv = make_uint4(hp[0], hp[1], hp[2], hp[3]);
  *lv = make_uint4(lp[0], lp[1], lp[2], lp[3]);
}
__device__ __forceinline__ bf16x8 u2b(uint4 u) {
  union { uint4 a; bf16x8 b; } x; x.a = u; return x.b;
}

// ---------------------------------------------------------------------------
// K1: sub0[b,n] = c[b,n,:].w0 ; qtermM[b,m] = q[b,m,:].w1 + bias[m] + MASK*(1-qm)
// ---------------------------------------------------------------------------
__global__ __launch_bounds__(256) void k_dots(
    const float* __restrict__ c, const float* __restrict__ q,
    const int* __restrict__ qmask,
    const float* __restrict__ w0, const float* __restrict__ w1,
    const float* __restrict__ bias,
    float* __restrict__ sub0, float* __restrict__ qtermM) {
  int wave = (blockIdx.x * blockDim.x + threadIdx.x) >> 6;
  int lane = threadIdx.x & 63;
  const int total = BB * NN + BB * MM;
  if (wave >= total) return;
  const float* row;
  const float* w;
  if (wave < BB * NN) { row = c + (size_t)wave * DD; w = w0; }
  else                { row = q + (size_t)(wave - BB * NN) * DD; w = w1; }
  float4 v  = *(const float4*)(row + lane * 4);
  float4 wv = *(const float4*)(w   + lane * 4);
  float s = v.x * wv.x + v.y * wv.y + v.z * wv.z + v.w * wv.w;
  #pragma unroll
  for (int off = 32; off > 0; off >>= 1) s += __shfl_xor(s, off, 64);
  if (lane == 0) {
    if (wave < BB * NN) {
      sub0[wave] = s;
    } else {
      int r = wave - BB * NN;
      int m = r & (MM - 1);
      qtermM[r] = s + bias[m] + (qmask[r] ? 0.0f : MASKV);
    }
  }
}

// zero colsum (ws is poisoned 0xAA each call)
__global__ __launch_bounds__(256) void k_zero(float* __restrict__ p) {
  p[blockIdx.x * 256 + threadIdx.x] = 0.0f;
}

// ---------------------------------------------------------------------------
// K_pack_q: q -> MFMA B-fragment bf16 hi/lo.  One (f,ks) combo per wave.
// ---------------------------------------------------------------------------
__global__ __launch_bounds__(256) void k_pack_q(
    const float* __restrict__ q,
    unsigned short* __restrict__ dsth, unsigned short* __restrict__ dstl) {
  const int b = blockIdx.y;
  const int u = blockIdx.x * 4 + (threadIdx.x >> 6);   // 0..63
  const int f = u >> 3, ks = u & 7;
  const int l = threadIdx.x & 63;
  const int l31 = l & 31, lh = l >> 5;
  const float* sb = q + (size_t)b * MM * DD + (size_t)(ks * 16 + lh * 8) * DD + f * 32 + l31;
  float ys[8];
  #pragma unroll
  for (int j = 0; j < 8; j++) ys[j] = sb[(size_t)j * DD];
  uint4 hv, lv;
  split8(ys, &hv, &lv);
  size_t off = (size_t)b * 32768 + (size_t)(u * 64 + l) * 8;
  *(uint4*)(dsth + off) = hv;
  *(uint4*)(dstl + off) = lv;
}

// ---------------------------------------------------------------------------
// K_pack_a: Anorm = (sum_p Apart[p]) / colsum -> B-fragment bf16 hi/lo.
// ---------------------------------------------------------------------------
__global__ __launch_bounds__(256) void k_pack_a(
    const float* __restrict__ Apart, const float* __restrict__ colsum,
    unsigned short* __restrict__ dsth, unsigned short* __restrict__ dstl) {
  const int b = blockIdx.y;
  const int u = blockIdx.x * 4 + (threadIdx.x >> 6);
  const int f = u >> 3, ks = u & 7;
  const int l = threadIdx.x & 63;
  const int l31 = l & 31, lh = l >> 5;
  const int m0 = ks * 16 + lh * 8;
  const size_t P = (size_t)BB * MM * DD;
  const float* sb = Apart + (size_t)b * MM * DD + (size_t)m0 * DD + f * 32 + l31;
  float ys[8];
  #pragma unroll
  for (int j = 0; j < 8; j++) {
    float v = sb[(size_t)j * DD] + sb[P + (size_t)j * DD] +
              sb[2 * P + (size_t)j * DD] + sb[3 * P + (size_t)j * DD];
    ys[j] = v * (1.0f / colsum[b * MM + m0 + j]);
  }
  uint4 hv, lv;
  split8(ys, &hv, &lv);
  size_t off = (size_t)b * 32768 + (size_t)(u * 64 + l) * 8;
  *(uint4*)(dsth + off) = hv;
  *(uint4*)(dstl + off) = lv;
}

// ---------------------------------------------------------------------------
// K2 (MFMA): sub2 tile GEMM via bf16x3 split, 128n x 128m per block.
// Epilogue emits BOTH consumers' preferred layouts via LDS transposes:
//  phase 1: S in k_out's A-fragment layout (Sfh/Sfl bf16 hi/lo, coalesced)
//  phase 2: E transposed (EThi/ETlo[b][m][n] bf16 hi/lo, coalesced)
// acc C/D layout: col = lane&31, row = (reg&3) + 8*(reg>>2) + 4*(lane>>5).
// ---------------------------------------------------------------------------
__global__ __launch_bounds__(256) void k_score(
    const float* __restrict__ c, const float* __restrict__ q,
    const int* __restrict__ cmask, const float* __restrict__ wm,
    const float* __restrict__ sub0, const float* __restrict__ qtermM,
    unsigned short* __restrict__ Sfh, unsigned short* __restrict__ Sfl,
    unsigned short* __restrict__ EThi, unsigned short* __restrict__ ETlo,
    float* __restrict__ colsum) {
  __shared__ unsigned short smem[32768];     // 64 KB, aliased below
  unsigned short* cwh = smem;                // [128][64] staging
  unsigned short* cwl = smem + 8192;
  unsigned short* qhi = smem + 16384;
  unsigned short* qlo = smem + 24576;
  const int b = blockIdx.y;
  const int n0 = blockIdx.x * 128;
  const int t = threadIdx.x;
  const int w = t >> 6;          // wave id: n rows [w*32, w*32+32)
  const int l = t & 63;
  const int l31 = l & 31;
  const int lh = l >> 5;

  f32x16 acc[4];
  #pragma unroll
  for (int mb = 0; mb < 4; mb++)
    #pragma unroll
    for (int i = 0; i < 16; i++) acc[mb][i] = 0.0f;

  for (int k0 = 0; k0 < DD; k0 += 64) {
    __syncthreads();
    #pragma unroll
    for (int g = 0; g < 4; g++) {
      int lin = t + g * 256;           // 0..1023
      int row = lin >> 3;              // 0..127
      int kg  = (lin & 7) * 8;         // 0..56
      unsigned boff = (unsigned)(row * 128 + ((kg * 2) ^ ((row & 7) << 4)));
      float4 w0v = *(const float4*)(wm + k0 + kg);
      float4 w1v = *(const float4*)(wm + k0 + kg + 4);
      const float* cp = c + (size_t)(b * NN + n0 + row) * DD + k0 + kg;
      float4 a0 = *(const float4*)cp;
      float4 a1 = *(const float4*)(cp + 4);
      float xs[8] = {a0.x * w0v.x, a0.y * w0v.y, a0.z * w0v.z, a0.w * w0v.w,
                     a1.x * w1v.x, a1.y * w1v.y, a1.z * w1v.z, a1.w * w1v.w};
      uint4 hv, lv;
      split8(xs, &hv, &lv);
      *(uint4*)((char*)cwh + boff) = hv;
      *(uint4*)((char*)cwl + boff) = lv;
      const float* qp = q + (size_t)(b * MM + row) * DD + k0 + kg;
      float4 b0 = *(const float4*)qp;
      float4 b1 = *(const float4*)(qp + 4);
      float ys[8] = {b0.x, b0.y, b0.z, b0.w, b1.x, b1.y, b1.z, b1.w};
      split8(ys, &hv, &lv);
      *(uint4*)((char*)qhi + boff) = hv;
      *(uint4*)((char*)qlo + boff) = lv;
    }
    __syncthreads();
    #pragma unroll
    for (int ks = 0; ks < 64; ks += 16) {
      int ak = ks + lh * 8;                        // 8 consecutive k per lane
      unsigned arow = (unsigned)(w * 32 + l31);
      unsigned aoff = arow * 128 + (((unsigned)(ak * 2)) ^ ((arow & 7) << 4));
      bf16x8 ah = *(const bf16x8*)((const char*)cwh + aoff);
      bf16x8 al = *(const bf16x8*)((const char*)cwl + aoff);
      #pragma unroll
      for (int mb = 0; mb < 4; mb++) {
        unsigned brow = (unsigned)(mb * 32 + l31);
        unsigned boff2 = brow * 128 + (((unsigned)(ak * 2)) ^ ((brow & 7) << 4));
        bf16x8 bh = *(const bf16x8*)((const char*)qhi + boff2);
        bf16x8 bl = *(const bf16x8*)((const char*)qlo + boff2);
        acc[mb] = __builtin_amdgcn_mfma_f32_32x32x16_bf16(ah, bh, acc[mb], 0, 0, 0);
        acc[mb] = __builtin_amdgcn_mfma_f32_32x32x16_bf16(ah, bl, acc[mb], 0, 0, 0);
        acc[mb] = __builtin_amdgcn_mfma_f32_32x32x16_bf16(al, bh, acc[mb], 0, 0, 0);
      }
    }
  }

  // --- epilogue; staging LDS is dead from here ---
  unsigned* stile = (unsigned*)smem;     // phase 1: [n][m] u32 (hi16|lo16<<16), 64 KB
  unsigned short* eth = smem;            // phase 2: [m][n] bf16 hi, 32 KB
  unsigned short* etl = smem + 16384;    //          [m][n] bf16 lo, 32 KB
  __syncthreads();                        // all waves done with staged MFMA reads

  float qt[4];
  #pragma unroll
  for (int mb = 0; mb < 4; mb++) qt[mb] = qtermM[b * MM + mb * 32 + l31];

  float s0m[16];
  float ps[4] = {0.f, 0.f, 0.f, 0.f};
  // phase 1: softmax -> S-tile LDS (u32 packed, swizzled), ps accumulation
  #pragma unroll
  for (int g = 0; g < 4; g++) {
    #pragma unroll
    for (int j = 0; j < 4; j++) {
      int r = 4 * g + j;
      int row = j + 8 * g + 4 * lh;
      int gn = n0 + w * 32 + row;
      float sv = sub0[b * NN + gn] + (cmask[b * NN + gn] ? 0.0f : MASKV);
      s0m[g * 4 + j] = sv;
      float x[4];
      float vmax = -FLT_MAX;
      #pragma unroll
      for (int mb = 0; mb < 4; mb++) { x[mb] = acc[mb][r] + qt[mb]; vmax = fmaxf(vmax, x[mb]); }
      #pragma unroll
      for (int off = 16; off > 0; off >>= 1) vmax = fmaxf(vmax, __shfl_xor(vmax, off, 64));
      float e[4];
      float vsum = 0.0f;
      #pragma unroll
      for (int mb = 0; mb < 4; mb++) { e[mb] = __expf(x[mb] - vmax); vsum += e[mb]; }
      #pragma unroll
      for (int off = 16; off > 0; off >>= 1) vsum += __shfl_xor(vsum, off, 64);
      float inv = 1.0f / vsum;
      int nloc = w * 32 + 8 * g + 4 * lh + j;
      unsigned swn = (unsigned)((nloc & 15) << 4);
      #pragma unroll
      for (int mb = 0; mb < 4; mb++) {
        float s = e[mb] * inv;
        unsigned short h = f2bf(s);
        unsigned short lo2 = f2bf(s - bf2f(h));
        unsigned v = (unsigned)h | ((unsigned)lo2 << 16);
        int m = mb * 32 + l31;
        *(unsigned*)((char*)stile + nloc * 512 + (((unsigned)(m * 4)) ^ swn)) = v;
        float Ev = __expf(acc[mb][r] + sv);   // exp(-1e30+x) underflows to 0 exactly
        ps[mb] += Ev;
      }
    }
  }
  #pragma unroll
  for (int mb = 0; mb < 4; mb++) {
    ps[mb] += __shfl_xor(ps[mb], 32, 64);    // combine the two half-wave row sets
    if (lh == 0) atomicAdd(&colsum[b * MM + mb * 32 + l31], ps[mb]);
  }
  __syncthreads();

  // coop coalesced Sf store: wave w -> local 32-row tile nt=w
  {
    size_t tb = ((size_t)b * 32 + (size_t)blockIdx.x * 4 + w) * 4096;
    int nloc = w * 32 + l31;
    unsigned basen = (unsigned)(nloc * 512);
    unsigned swn = (unsigned)((nloc & 15) << 4);
    #pragma unroll
    for (int ks = 0; ks < 8; ks++) {
      unsigned mB = (unsigned)((lh * 8 + ks * 16) * 4);
      uint4 va = *(const uint4*)((const char*)stile + basen + (mB ^ swn));
      uint4 vb = *(const uint4*)((const char*)stile + basen + ((mB + 16) ^ swn));
      uint4 hv = make_uint4((va.x & 0xFFFFu) | (va.y << 16), (va.z & 0xFFFFu) | (va.w << 16),
                            (vb.x & 0xFFFFu) | (vb.y << 16), (vb.z & 0xFFFFu) | (vb.w << 16));
      uint4 lv = make_uint4((va.x >> 16) | (va.y & 0xFFFF0000u), (va.z >> 16) | (va.w & 0xFFFF0000u),
                            (vb.x >> 16) | (vb.y & 0xFFFF0000u), (vb.z >> 16) | (vb.w & 0xFFFF0000u));
      size_t off = tb + (size_t)(ks * 64 + l) * 8;
      *(uint4*)(Sfh + off) = hv;
      *(uint4*)(Sfl + off) = lv;
    }
  }
  __syncthreads();

  // phase 2: recompute E from live acc -> swizzled ET tile
  #pragma unroll
  for (int g = 0; g < 4; g++) {
    float evg[4][4];
    #pragma unroll
    for (int j = 0; j < 4; j++) {
      int r = 4 * g + j;
      #pragma unroll
      for (int mb = 0; mb < 4; mb++)
        evg[mb][j] = __expf(acc[mb][r] + s0m[g * 4 + j]);
    }
    int nloc = w * 32 + 8 * g + 4 * lh;
    #pragma unroll
    for (int mb = 0; mb < 4; mb++) {
      int m = mb * 32 + l31;
      unsigned short h[4], lo[4];
      #pragma unroll
      for (int j = 0; j < 4; j++) {
        h[j] = f2bf(evg[mb][j]);
        lo[j] = f2bf(evg[mb][j] - bf2f(h[j]));
      }
      unsigned addr = (unsigned)(m * 256 + ((nloc * 2) ^ ((m & 15) << 4)));
      *(uint2*)((char*)eth + addr) = make_uint2(
          (unsigned)h[0] | ((unsigned)h[1] << 16),
          (unsigned)h[2] | ((unsigned)h[3] << 16));
      *(uint2*)((char*)etl + addr) = make_uint2(
          (unsigned)lo[0] | ((unsigned)lo[1] << 16),
          (unsigned)lo[2] | ((unsigned)lo[3] << 16));
    }
  }
  __syncthreads();

  // cooperative coalesced ET store: wave = 4 m-rows x 16 chunks of 16B
  {
    int chunk = t & 15;                    // 16B chunk within 256B row
    int mrow0 = t >> 4;                    // 0..15
    #pragma unroll
    for (int it = 0; it < 8; it++) {
      int m = it * 16 + mrow0;
      int sw = (chunk * 16) ^ ((m & 15) << 4);
      uint4 vh = *(const uint4*)((const char*)eth + m * 256 + sw);
      uint4 vl = *(const uint4*)((const char*)etl + m * 256 + sw);
      size_t gb = (size_t)(b * MM + m) * NN + n0 + chunk * 8;
      *(uint4*)(EThi + gb) = vh;
      *(uint4*)(ETlo + gb) = vl;
    }
  }
}

// ---------------------------------------------------------------------------
// K4 (MFMA): Apart[p][b][m][d] = sum_{n in chunk p} ET[m][n] * c[n][d]
// ---------------------------------------------------------------------------
__global__ __launch_bounds__(512) void k_colA(
    const unsigned short* __restrict__ EThi, const unsigned short* __restrict__ ETlo,
    const float* __restrict__ c, float* __restrict__ Apart) {
  const int p = blockIdx.x;
  const int b = blockIdx.y;
  const int t = threadIdx.x;
  const int w = t >> 6;
  const int l = t & 63;
  const int l31 = l & 31, lh = l >> 5;
  const int d = w * 32 + l31;

  f32x16 acc[4];
  #pragma unroll
  for (int mf = 0; mf < 4; mf++)
    #pragma unroll
    for (int i = 0; i < 16; i++) acc[mf][i] = 0.0f;

  const float* cb = c + (size_t)b * NN * DD + d;
  const size_t etb = (size_t)b * MM * NN + (size_t)p * 256 + lh * 8;

  for (int ks = 0; ks < 16; ks++) {
    int nb = p * 256 + ks * 16 + lh * 8;
    float ys[8];
    #pragma unroll
    for (int j = 0; j < 8; j++) ys[j] = cb[(size_t)(nb + j) * DD];
    uint4 hv, lv;
    split8(ys, &hv, &lv);
    bf16x8 ah = u2b(hv), al = u2b(lv);
    #pragma unroll
    for (int mf = 0; mf < 4; mf++) {
      size_t eoff = etb + (size_t)(mf * 32 + l31) * NN + ks * 16;
      bf16x8 bh = *(const bf16x8*)(EThi + eoff);
      bf16x8 bl = *(const bf16x8*)(ETlo + eoff);
      acc[mf] = __builtin_amdgcn_mfma_f32_32x32x16_bf16(ah, bh, acc[mf], 0, 0, 0);
      acc[mf] = __builtin_amdgcn_mfma_f32_32x32x16_bf16(ah, bl, acc[mf], 0, 0, 0);
      acc[mf] = __builtin_amdgcn_mfma_f32_32x32x16_bf16(al, bh, acc[mf], 0, 0, 0);
    }
  }

  float* ap = Apart + (size_t)p * (BB * MM * DD);
  #pragma unroll
  for (int mf = 0; mf < 4; mf++) {
    size_t rowb = (size_t)(b * MM + mf * 32 + l31) * DD + w * 32 + 4 * lh;
    #pragma unroll
    for (int g = 0; g < 4; g++) {
      float4 o = make_float4(acc[mf][4 * g + 0], acc[mf][4 * g + 1],
                             acc[mf][4 * g + 2], acc[mf][4 * g + 3]);
      *(float4*)(ap + rowb + 8 * g) = o;
    }
  }
}

// ---------------------------------------------------------------------------
// K5 (MFMA): c2q = S @ q ; q2c = S @ Anorm ; out = [c, c2q, c*c2q, c*q2c]
// All operands pre-packed in fragment layout: per ks just 6 coalesced 16B
// loads + 6 MFMA.  grid (32, BB), 8 waves; wave w = d-frag, both GEMMs.
// ---------------------------------------------------------------------------
__global__ __launch_bounds__(512, 4) void k_out(
    const float* __restrict__ c,
    const unsigned short* __restrict__ Sfh, const unsigned short* __restrict__ Sfl,
    const unsigned short* __restrict__ qfh, const unsigned short* __restrict__ qfl,
    const unsigned short* __restrict__ afh, const unsigned short* __restrict__ afl,
    float* __restrict__ out) {
  const int b = blockIdx.y;
  const int n0 = blockIdx.x * 32;
  const int t = threadIdx.x;
  const int w = t >> 6;            // wave id == d-frag f
  const int l = t & 63;
  const int l31 = l & 31;
  const int lh = l >> 5;

  f32x16 acc0, acc1;
  #pragma unroll
  for (int i = 0; i < 16; i++) { acc0[i] = 0.0f; acc1[i] = 0.0f; }

  const size_t so = ((size_t)b * 32 + blockIdx.x) * 4096 + (size_t)l * 8;
  const size_t fo = (size_t)b * 32768 + (size_t)(w * 8 * 64 + l) * 8;

  #pragma unroll
  for (int ks = 0; ks < 8; ks++) {
    bf16x8 ah = *(const bf16x8*)(Sfh + so + ks * 512);
    bf16x8 al = *(const bf16x8*)(Sfl + so + ks * 512);
    size_t off = fo + (size_t)(ks * 64) * 8;
    bf16x8 qh = *(const bf16x8*)(qfh + off);
    bf16x8 ql = *(const bf16x8*)(qfl + off);
    bf16x8 vh = *(const bf16x8*)(afh + off);
    bf16x8 vl = *(const bf16x8*)(afl + off);
    acc0 = __builtin_amdgcn_mfma_f32_32x32x16_bf16(ah, qh, acc0, 0, 0, 0);
    acc0 = __builtin_amdgcn_mfma_f32_32x32x16_bf16(ah, ql, acc0, 0, 0, 0);
    acc0 = __builtin_amdgcn_mfma_f32_32x32x16_bf16(al, qh, acc0, 0, 0, 0);
    acc1 = __builtin_amdgcn_mfma_f32_32x32x16_bf16(ah, vh, acc1, 0, 0, 0);
    acc1 = __builtin_amdgcn_mfma_f32_32x32x16_bf16(ah, vl, acc1, 0, 0, 0);
    acc1 = __builtin_amdgcn_mfma_f32_32x32x16_bf16(al, vh, acc1, 0, 0, 0);
  }

  const int d = w * 32 + l31;
  #pragma unroll
  for (int r = 0; r < 16; r++) {
    int row = (r & 3) + 8 * (r >> 2) + 4 * lh;
    int gn = n0 + row;
    float cv = c[(size_t)(b * NN + gn) * DD + d];
    size_t ob = (size_t)(b * NN + gn) * (4 * DD) + d;
    float v1 = acc0[r], v3 = acc1[r];
    out[ob]          = cv;
    out[ob + DD]     = v1;
    out[ob + 2 * DD] = cv * v1;
    out[ob + 3 * DD] = cv * v3;
  }
}

// ---------------------------------------------------------------------------
extern "C" void kernel_launch(void* const* d_in, const int* in_sizes, int n_in,
                              void* d_out, int out_size, void* d_ws, size_t ws_size,
                              hipStream_t stream) {
  const float* c     = (const float*)d_in[0];
  const float* q     = (const float*)d_in[1];
  const int*   cmask = (const int*)d_in[2];
  const int*   qmask = (const int*)d_in[3];
  const float* w0    = (const float*)d_in[4];
  const float* w1    = (const float*)d_in[5];
  const float* wm    = (const float*)d_in[6];
  const float* bias  = (const float*)d_in[7];
  float* out = (float*)d_out;
  float* ws  = (float*)d_ws;

  unsigned short* Sfh  = (unsigned short*)ws;                // 8388608 u16
  unsigned short* Sfl  = Sfh + 8388608;                      // 8388608 u16
  unsigned short* EThi = (unsigned short*)(ws + 8388608);    // 8388608 u16
  unsigned short* ETlo = (unsigned short*)(ws + 12582912);   // 8388608 u16
  float* Apart  = ws + 16777216;                             // 4 * 2097152 f
  unsigned short* qfh = (unsigned short*)(ws + 25165824);    // 2097152 u16
  unsigned short* qfl = (unsigned short*)(ws + 26214400);
  unsigned short* afh = (unsigned short*)(ws + 27262976);
  unsigned short* afl = (unsigned short*)(ws + 28311552);
  float* sub0   = ws + 29360128;                             // 65536 f
  float* qtermM = ws + 29425664;                             // 8192 f
  float* colsum = ws + 29433856;                             // 8192 f

  k_dots<<<18432, 256, 0, stream>>>(c, q, qmask, w0, w1, bias, sub0, qtermM);
  k_zero<<<32, 256, 0, stream>>>(colsum);
  k_pack_q<<<dim3(16, BB), 256, 0, stream>>>(q, qfh, qfl);
  k_score<<<dim3(8, BB), 256, 0, stream>>>(c, q, cmask, wm, sub0, qtermM, Sfh, Sfl, EThi, ETlo, colsum);
  k_colA<<<dim3(4, BB), 512, 0, stream>>>(EThi, ETlo, c, Apart);
  k_pack_a<<<dim3(16, BB), 256, 0, stream>>>(Apart, colsum, afh, afl);
  k_out<<<dim3(32, BB), 512, 0, stream>>>(c, Sfh, Sfl, qfh, qfl, afh, afl, out);
}